// Round 11
// baseline (973.744 us; speedup 1.0000x reference)
//
#include <hip/hip_runtime.h>
#include <hip/hip_fp16.h>

#define NB 8
#define NPTS 4096
#define NS 1024
#define NK 32
#define NM (NB*NS*NK)   // 262144 grouped points
#define NWORK 504       // fused worker blocks (grid = 8 + NWORK = 512 <= guaranteed residency)

typedef _Float16 f16x8 __attribute__((ext_vector_type(8)));
typedef float    f32x4 __attribute__((ext_vector_type(4)));
typedef float    f32x2 __attribute__((ext_vector_type(2)));

__device__ __forceinline__ float bf2f(unsigned short u){ return __uint_as_float(((unsigned)u)<<16); }
__device__ __forceinline__ unsigned short f2bf(float f){
  unsigned u = __float_as_uint(f);
  u = u + 0x7fffu + ((u>>16)&1u);   // RNE
  return (unsigned short)(u>>16);
}
__device__ __forceinline__ unsigned long long umax64(unsigned long long a, unsigned long long b){ return a>b?a:b; }

// ---- DPP wave64 reduce: row_shr 1/2/4/8 + row_bcast 15/31, result in lane 63.
#define DPP_STEP_MAX(x, ctrl, rm) { \
  unsigned _t = (unsigned)__builtin_amdgcn_update_dpp((int)(x), (int)(x), (ctrl), (rm), 0xf, false); \
  (x) = ((x) > _t) ? (x) : _t; }

__device__ __forceinline__ unsigned wave_max_u32(unsigned x){
  DPP_STEP_MAX(x, 0x111, 0xf);
  DPP_STEP_MAX(x, 0x112, 0xf);
  DPP_STEP_MAX(x, 0x114, 0xf);
  DPP_STEP_MAX(x, 0x118, 0xf);
  DPP_STEP_MAX(x, 0x142, 0xa);
  DPP_STEP_MAX(x, 0x143, 0xc);
  return (unsigned)__builtin_amdgcn_readlane((int)x, 63);
}

// Runtime dtype detection (block-uniform scalar branch): f32 data read as bf16
// halves decodes huge/denormal or exact-zero; true bf16 N(0,1) does not.
__device__ __forceinline__ bool detect_f32(const unsigned short* __restrict__ u){
  int huge_=0, zero_=0;
  #pragma unroll
  for (int i=0;i<64;i++){
    unsigned short w = u[i];
    if ((w & 0x7fffu) == 0) { zero_++; continue; }
    float a = fabsf(bf2f(w));
    if (a > 1e6f || a < 1e-6f) huge_++;
  }
  return (huge_ >= 8) || (zero_ >= 24);
}
__device__ __forceinline__ float ldin(const void* p, size_t i, bool f32){
  if (f32) return ((const float*)p)[i];
  else     return bf2f(((const unsigned short*)p)[i]);
}

// ---------------------------------------------------------------------------
// Fused FPS + feat_transpose + kNN (producer-consumer, one launch).
// R11: 512-thread blocks (8 waves). FPS: 8 pts/lane (was 16) — halves the
// per-lane dist-update issue (the largest reducible term of the serial
// chain) and halves the local max-tree/li-scan; cross-wave combine widens
// to 8 partials (broadcast LDS reads, +~10 cyc). Identical RN arithmetic
// per point, identical tie-break (max dist, then min global index) ->
// bit-identical FPS output. Workers re-indexed for 512 threads; knn's
// rank-sort is a total order over unique keys -> knn_idx content unchanged.
// Residency: 512 blocks x 65.7 KB LDS -> exactly 2 blocks/CU, 1024 threads
// <= 2048; launch_bounds(512,4) caps VGPR at 128.
// ---------------------------------------------------------------------------
__global__ __launch_bounds__(512, 4) void fps_knn_fused(
    const void* __restrict__ pc1,
    const void* __restrict__ feats,
    int* __restrict__ fps_out,
    _Float16* __restrict__ G,
    float* __restrict__ statz,
    float* __restrict__ new_xyz,
    int* __restrict__ knn_idx)
{
  __shared__ __align__(16) char smem[65664];
  int t = threadIdx.x;
  const bool f32 = detect_f32((const unsigned short*)pc1);
  if (blockIdx.x < 8){
    __builtin_amdgcn_s_setprio(1);     // FPS is the global critical path
    float4* cp4 = (float4*)smem;
    unsigned long long (*part)[8] = (unsigned long long (*)[8])(smem + 65536);  // 2x64 B
    int b = blockIdx.x;
    const size_t base = (size_t)b*3*NPTS;
    for (int i=t;i<NPTS;i+=512){
      float4 v;
      v.x = ldin(pc1, base+i, f32);
      v.y = ldin(pc1, base+NPTS+i, f32);
      v.z = ldin(pc1, base+2*NPTS+i, f32);
      v.w = 0.f;
      cp4[i] = v;
    }
    __syncthreads();
    f32x2 px[4],py[4],pz[4],dist[4];
    #pragma unroll
    for (int j=0;j<4;j++){
      float4 a = cp4[t*8+2*j], c = cp4[t*8+2*j+1];
      px[j] = f32x2{a.x, c.x};
      py[j] = f32x2{a.y, c.y};
      pz[j] = f32x2{a.z, c.z};
      dist[j] = f32x2{1e10f, 1e10f};
    }
    int far = 0;
    int w = t>>6, lane = t&63;
    for (int it=0; it<NS; it++){
      if (t==0)
        __hip_atomic_store(&fps_out[b*NS+it], far, __ATOMIC_RELAXED, __HIP_MEMORY_SCOPE_AGENT);
      float4 cc = cp4[far];
      f32x2 vcx = f32x2{cc.x,cc.x}, vcy = f32x2{cc.y,cc.y}, vcz = f32x2{cc.z,cc.z};
      {
        #pragma clang fp contract(off)
        #pragma unroll
        for (int j=0;j<4;j++){
          f32x2 dx = px[j]-vcx, dy = py[j]-vcy, dz = pz[j]-vcz;
          f32x2 d  = (dx*dx + dy*dy) + dz*dz;     // exact RN order: ((x2+y2)+z2)
          dist[j]  = __builtin_elementwise_min(dist[j], d);
        }
      }
      float d_[8];
      #pragma unroll
      for (int j=0;j<4;j++){ d_[2*j]=dist[j][0]; d_[2*j+1]=dist[j][1]; }
      float a0 = fmaxf(fmaxf(d_[0],d_[1]),d_[2]);      // -> v_max3_f32
      float a1 = fmaxf(fmaxf(d_[3],d_[4]),d_[5]);
      float a2 = fmaxf(d_[6],d_[7]);
      float bl = fmaxf(fmaxf(a0,a1),a2);               // exact max of 8
      int li = 0;
      #pragma unroll
      for (int i=7;i>=0;i--) if (d_[i]==bl) li = i;    // descending: final = lowest i
      unsigned blu = __float_as_uint(bl);               // dist>=0: bits monotone
      unsigned wm = wave_max_u32(blu);
      unsigned long long mk = __ballot(blu == wm);
      int l = __builtin_ctzll(mk);                      // lowest lane = lowest n
      int idx = __builtin_amdgcn_readlane(t*8+li, l);
      if (lane==0) part[it&1][w] = ((unsigned long long)wm<<32) | (unsigned)(NPTS-1-idx);
      __syncthreads();
      const ulonglong2* pp = (const ulonglong2*)&part[it&1][0];
      ulonglong2 A = pp[0], B = pp[1], C2 = pp[2], D = pp[3];   // broadcast reads
      unsigned long long m = umax64(umax64(umax64(A.x,A.y), umax64(B.x,B.y)),
                                    umax64(umax64(C2.x,C2.y), umax64(D.x,D.y)));
      far = NPTS-1 - (int)(m & 0xffffffffu);
    }
  } else {
    int wid = blockIdx.x - 8;
    // ---------------- phase 1: feats transpose -> G (grid-stride tiles) ----
    {
      float (*tile)[65] = (float (*)[65])smem;
      if (wid==0){
        for (int i=t;i<6144;i+=512) statz[i]=0.f;
      }
      for (int b2 = wid; b2 < 512; b2 += NWORK){
        int b = b2>>6, n0 = (b2&63)*64;
        #pragma unroll 4
        for (int i=0;i<16;i++){
          int idx = i*512 + t;
          int c = idx>>6, n = idx&63;
          tile[c][n] = ldin(feats, ((size_t)b*128 + c)*NPTS + n0 + n, f32);
        }
        __syncthreads();
        #pragma unroll 4
        for (int i=0;i<16;i++){
          int idx = i*512 + t;
          int n = idx>>7, c = idx&127;
          G[((size_t)b*NPTS + n0 + n)*136 + 3 + c] = (_Float16)tile[c][n];
        }
        if (t<64){
          size_t gb = ((size_t)b*NPTS + n0 + t)*136;
          G[gb]=(_Float16)0.f; G[gb+1]=(_Float16)0.f; G[gb+2]=(_Float16)0.f;
          #pragma unroll
          for (int c=131;c<136;c++) G[gb+c]=(_Float16)0.f;
        }
        __syncthreads();
      }
    }
    __syncthreads();
    // ---------------- phase 2: kNN centers (grid-stride, production order) -
    unsigned* hist            = (unsigned*)smem;                       // 16384 B
    unsigned long long* cand  = (unsigned long long*)(smem + 16384);   //  4096 B
    unsigned* partk           = (unsigned*)(smem + 20480);             //  1024 B
    unsigned* sup             = (unsigned*)(smem + 21504);             //    64 B
    unsigned* scal            = (unsigned*)(smem + 21568);             //     8 B
    int* sn0                  = (int*)(smem + 21576);
    for (int ci = wid; ci < NB*NS; ci += NWORK){
      int b = ci & 7, s = ci >> 3;          // consume in production order
      int blk = (b<<10) | s;
      if (t==0){
        int nv;
        while ((nv = __hip_atomic_load(&fps_out[b*NS+s], __ATOMIC_RELAXED,
                                       __HIP_MEMORY_SCOPE_AGENT)) == -1)
          __builtin_amdgcn_s_sleep(16);
        *sn0 = nv;
      }
      __syncthreads();
      const size_t base = (size_t)b*3*NPTS;
      int n0 = *sn0;
      float qx = ldin(pc1, base+n0, f32);
      float qy = ldin(pc1, base+NPTS+n0, f32);
      float qz = ldin(pc1, base+2*NPTS+n0, f32);
      if (t==0){
        new_xyz[(size_t)blk*3]=qx; new_xyz[(size_t)blk*3+1]=qy; new_xyz[(size_t)blk*3+2]=qz;
        scal[0]=0u;
      }
      #pragma unroll
      for (int j=0;j<8;j++) hist[j*512 + t] = 0u;
      float qn = __fadd_rn(__fadd_rn(__fmul_rn(qx,qx),__fmul_rn(qy,qy)),__fmul_rn(qz,qz));
      unsigned dv[8];
      #pragma unroll
      for (int k=0;k<8;k++){
        int n = t + 512*k;                               // coalesced global reads
        float x = ldin(pc1, base+n, f32);
        float y = ldin(pc1, base+NPTS+n, f32);
        float z = ldin(pc1, base+2*NPTS+n, f32);
        float pn = __fadd_rn(__fadd_rn(__fmul_rn(x,x),__fmul_rn(y,y)),__fmul_rn(z,z));
        float dt = __fadd_rn(__fadd_rn(__fmul_rn(qx,x),__fmul_rn(qy,y)),__fmul_rn(qz,z));
        float d  = __fsub_rn(__fadd_rn(qn,pn), __fmul_rn(2.f,dt));
        unsigned u = __float_as_uint(d);
        dv[k] = (u & 0x80000000u) ? ~u : (u | 0x80000000u);  // order-preserving map
      }
      __syncthreads();
      #pragma unroll
      for (int k=0;k<8;k++)
        atomicAdd(&hist[dv[k]>>20], 1u);
      __syncthreads();
      if (t < 256){
        unsigned ssum = 0;
        const uint4* hp = (const uint4*)&hist[t*16];
        #pragma unroll
        for (int j=0;j<4;j++){
          uint4 v = hp[j];
          ssum += v.x + v.y + v.z + v.w;
        }
        partk[t] = ssum;
      }
      __syncthreads();
      if (t < 16){
        unsigned qq = 0;
        #pragma unroll
        for (int j=0;j<16;j++) qq += partk[t*16 + j];
        sup[t] = qq;
      }
      __syncthreads();
      if (t == 0){
        unsigned acc = 0; int sb = 0;
        for (; sb < 16; sb++){ unsigned v = sup[sb]; if (acc + v >= NK) break; acc += v; }
        int pt = sb*16;
        for (; pt < sb*16+16; pt++){ unsigned v = partk[pt]; if (acc + v >= NK) break; acc += v; }
        int bn = pt*16;
        for (; bn < pt*16+16; bn++){ unsigned v = hist[bn]; if (acc + v >= NK) break; acc += v; }
        scal[1] = (unsigned)bn;
      }
      __syncthreads();
      unsigned beta = scal[1];
      #pragma unroll
      for (int k=0;k<8;k++){
        if ((dv[k]>>20) <= beta){
          unsigned pos = atomicAdd(&scal[0], 1u);
          if (pos < 512u)
            cand[pos] = ((unsigned long long)dv[k]<<32) | (unsigned)(t + 512*k);
        }
      }
      __syncthreads();
      int C = (int)scal[0]; if (C > 512) C = 512;
      for (int tt = t; tt < C; tt += 512){
        unsigned long long K = cand[tt];
        int rank = 0;
        for (int j = 0; j < C; j++) rank += (cand[j] < K) ? 1 : 0;   // broadcast reads
        if (rank < NK) knn_idx[(size_t)blk*NK + rank] = (int)(K & 0xffffffffu);
      }
      __syncthreads();   // smem reused next center
    }
  }
}

// ---------------------------------------------------------------------------
// MFMA conv (R10 verbatim). LAYER 1: wt LDS staging + barriers; K=131 ragged.
// LAYER 2/3: barrier-free K-loop — B-fragments direct from global W (L2-hot),
// #pragma unroll 2 (R10-verified ~-20 us). LAYER 3 epilogue emits the
// per-center max over 32 neighbor rows (R8 exact max-fold).
// ---------------------------------------------------------------------------
template<int LAYER>
__global__ __launch_bounds__(256)
__attribute__((amdgpu_waves_per_eu(1,3)))
void conv_mfma(
    const void* __restrict__ pc1,
    const _Float16* __restrict__ G,
    const int* __restrict__ knn_idx,
    const float* __restrict__ new_xyz,
    const _Float16* __restrict__ Hin,
    const float* __restrict__ gp1,
    const float* __restrict__ gp2,
    const void* __restrict__ W,
    _Float16* __restrict__ Hout,
    float* __restrict__ gs1, float* __restrict__ gs2)
{
  constexpr int KC  = (LAYER==1)?131:128;
  constexpr int KCP = (LAYER==1)?160:128;
  constexpr int HSW = (LAYER==1)?168:136;
  __shared__ __align__(16) _Float16 hs[128][HSW];
  __shared__ __align__(16) _Float16 wt[(LAYER==1)?128:1][40];
  __shared__ float red1[4][64], red2[4][64];
  __shared__ int   nidx[128];
  __shared__ float cxyz[4][3];
  __shared__ __align__(16) _Float16 smuh[128], srsh[128];
  int blk = blockIdx.x;
  int m0 = blk*128;
  int b  = m0 >> 15;
  int t  = threadIdx.x;
  const bool f32 = detect_f32((const unsigned short*)pc1);
  int w = t>>6, lane = t&63;
  int l16 = lane&15, q = lane>>4, q8 = q*8;
  int wr = (w&1)*64, wc = (w>>1)*64;

  if (LAYER==1){
    if (t<128) nidx[t] = knn_idx[m0+t];
    if (t<12)  cxyz[t/3][t%3] = new_xyz[(size_t)(m0>>5)*3 + t];
    __syncthreads();
    for (int u=t; u<128*17; u+=256){
      int p = u/17, qq = u - p*17;
      const f16x8* src = (const f16x8*)(G + ((size_t)b*NPTS + nidx[p])*136 + qq*8);
      *(f16x8*)&hs[p][qq*8] = *src;
    }
    for (int u=t; u<128*3; u+=256){
      int p = u/3, qq = u - p*3;
      uint4 z; z.x=z.y=z.z=z.w=0u;
      *(uint4*)&hs[p][136+qq*8] = z;
    }
    __syncthreads();
    if (t<128){
      int n = nidx[t];
      float cx = cxyz[t>>5][0], cy = cxyz[t>>5][1], cz = cxyz[t>>5][2];
      hs[t][0] = (_Float16)(ldin(pc1, ((size_t)b*3+0)*NPTS+n, f32) - cx);
      hs[t][1] = (_Float16)(ldin(pc1, ((size_t)b*3+1)*NPTS+n, f32) - cy);
      hs[t][2] = (_Float16)(ldin(pc1, ((size_t)b*3+2)*NPTS+n, f32) - cz);
    }
    __syncthreads();
  } else {
    if (t<128){
      const float inv = 1.0f/32768.0f;
      float m = gp1[b*128+t]*inv;
      smuh[t] = (_Float16)m;
      srsh[t] = (_Float16)rsqrtf(gp2[b*128+t]*inv - m*m + 1e-5f);
    }
    __syncthreads();
    int p = t & 127, hi = t>>7;
    const _Float16* src = Hin + (size_t)(m0+p)*128 + hi*64;
    f16x8 zero8 = {};
    #pragma unroll
    for (int j=0;j<8;j++){
      f16x8 v   = *(const f16x8*)(src + j*8);
      f16x8 mu8 = *(const f16x8*)&smuh[hi*64 + j*8];
      f16x8 rs8 = *(const f16x8*)&srsh[hi*64 + j*8];
      f16x8 o = (v - mu8) * rs8;                    // v_pk_*_f16
      o = __builtin_elementwise_max(o, zero8);      // relu
      *(f16x8*)&hs[p][hi*64 + j*8] = o;
    }
    __syncthreads();
  }

  f32x4 acc[4][4];
  #pragma unroll
  for (int i=0;i<4;i++)
    #pragma unroll
    for (int c=0;c<4;c++){ acc[i][c][0]=0.f; acc[i][c][1]=0.f; acc[i][c][2]=0.f; acc[i][c][3]=0.f; }

  if (LAYER==1){
    for (int k0=0; k0<KCP; k0+=32){
      {
        int o = t>>1, half = t&1;
        f16x8 w0, w1;
        #pragma unroll
        for (int jj=0;jj<8;jj++){
          int c0 = k0 + half*16 + jj, c1 = c0 + 8;
          w0[jj] = (_Float16)((c0<KC) ? ldin(W, (size_t)o*KC + c0, f32) : 0.f);
          w1[jj] = (_Float16)((c1<KC) ? ldin(W, (size_t)o*KC + c1, f32) : 0.f);
        }
        *(f16x8*)&wt[o][half*16]     = w0;
        *(f16x8*)&wt[o][half*16 + 8] = w1;
      }
      __syncthreads();
      f16x8 av[4], bv[4];
      #pragma unroll
      for (int i=0;i<4;i++) av[i] = *(const f16x8*)&hs[wr + i*16 + l16][k0 + q8];
      #pragma unroll
      for (int c=0;c<4;c++) bv[c] = *(const f16x8*)&wt[wc + c*16 + l16][q8];
      #pragma unroll
      for (int i=0;i<4;i++)
        #pragma unroll
        for (int c=0;c<4;c++)
          acc[i][c] = __builtin_amdgcn_mfma_f32_16x16x32_f16(av[i], bv[c], acc[i][c], 0,0,0);
      __syncthreads();
    }
  } else {
    // barrier-free K-loop: B-frags direct from global (L2-hot), A from LDS.
    // unroll 2 — halves in-flight loads / VGPR pressure.
    #pragma unroll 2
    for (int k0=0; k0<128; k0+=32){
      f16x8 av[4], bv[4];
      #pragma unroll
      for (int i=0;i<4;i++) av[i] = *(const f16x8*)&hs[wr + i*16 + l16][k0 + q8];
      #pragma unroll
      for (int c=0;c<4;c++){
        int row = wc + c*16 + l16;
        if (f32){
          const f32x4* Wr = (const f32x4*)((const float*)W + (size_t)row*128 + k0 + q8);
          f32x4 v0 = Wr[0], v1 = Wr[1];
          f16x8 bb;
          bb[0]=(_Float16)v0[0]; bb[1]=(_Float16)v0[1]; bb[2]=(_Float16)v0[2]; bb[3]=(_Float16)v0[3];
          bb[4]=(_Float16)v1[0]; bb[5]=(_Float16)v1[1]; bb[6]=(_Float16)v1[2]; bb[7]=(_Float16)v1[3];
          bv[c] = bb;
        } else {
          const ushort4* Wr = (const ushort4*)((const unsigned short*)W + (size_t)row*128 + k0 + q8);
          ushort4 u0 = Wr[0], u1 = Wr[1];
          f16x8 bb;
          bb[0]=(_Float16)bf2f(u0.x); bb[1]=(_Float16)bf2f(u0.y); bb[2]=(_Float16)bf2f(u0.z); bb[3]=(_Float16)bf2f(u0.w);
          bb[4]=(_Float16)bf2f(u1.x); bb[5]=(_Float16)bf2f(u1.y); bb[6]=(_Float16)bf2f(u1.z); bb[7]=(_Float16)bf2f(u1.w);
          bv[c] = bb;
        }
      }
      #pragma unroll
      for (int i=0;i<4;i++)
        #pragma unroll
        for (int c=0;c<4;c++)
          acc[i][c] = __builtin_amdgcn_mfma_f32_16x16x32_f16(av[i], bv[c], acc[i][c], 0,0,0);
    }
    __syncthreads();   // all waves done reading hs before epilogue overwrites
  }

  // epilogue: stats from f32 acc + C -> hs (f16) -> global
  #pragma unroll
  for (int c=0;c<4;c++){
    int o = wc + c*16 + l16;
    float s1=0.f, s2=0.f;
    #pragma unroll
    for (int i=0;i<4;i++){
      int row = wr + i*16 + q*4;
      #pragma unroll
      for (int r=0;r<4;r++){
        float v = acc[i][c][r];
        hs[row + r][o] = (_Float16)v;
        s1 += v; s2 = fmaf(v,v,s2);
      }
    }
    s1 += __shfl_xor(s1, 16, 64); s1 += __shfl_xor(s1, 32, 64);
    s2 += __shfl_xor(s2, 16, 64); s2 += __shfl_xor(s2, 32, 64);
    if (q==0){ red1[w][c*16+l16] = s1; red2[w][c*16+l16] = s2; }
  }
  __syncthreads();
  if (LAYER==3){
    // per-center max over the 32 neighbor rows -> M[center][c] (f16).
    if (t<128){
      #pragma unroll
      for (int c4=0;c4<4;c4++){
        _Float16 mx = hs[c4*32][t];
        #pragma unroll
        for (int r=1;r<32;r++){
          _Float16 v = hs[c4*32 + r][t];
          mx = (v > mx) ? v : mx;
        }
        Hout[(size_t)(blk*4 + c4)*128 + t] = mx;   // 256B coalesced per c4
      }
    }
  } else {
    _Float16* dst0 = Hout + (size_t)m0*128;
    #pragma unroll
    for (int j=0;j<8;j++){
      int fi = j*256 + t;
      int row = fi >> 4, col = (fi & 15)*8;
      *(f16x8*)(dst0 + (size_t)fi*8) = *(const f16x8*)&hs[row][col];
    }
  }
  if (t<128){
    int lo = t & 63, g = (t>>6)*2;
    unsafeAtomicAdd(&gs1[b*128+t], red1[g][lo] + red1[g+1][lo]);
    unsafeAtomicAdd(&gs2[b*128+t], red2[g][lo] + red2[g+1][lo]);
  }
}

// ---------------------------------------------------------------------------
// Final (R8): M already holds max_k h (per center, 128 ch). Just norm+relu
// per channel, then fc 128->3. Reads 2 MB instead of 67 MB.
// ---------------------------------------------------------------------------
__global__ __launch_bounds__(128) void final_kernel(
    const void* __restrict__ pc1,
    const _Float16* __restrict__ M,
    const float* __restrict__ gp1, const float* __restrict__ gp2,
    const void* __restrict__ fc_w, const void* __restrict__ fc_b,
    void* __restrict__ outv)
{
  __shared__ float mv[128];
  int blk = blockIdx.x;       // b*1024+s
  int b = blk>>10, s = blk & 1023;
  int o = threadIdx.x;
  const bool f32 = detect_f32((const unsigned short*)pc1);
  float mraw = (float)M[(size_t)blk*128 + o];   // exact f16->f32
  int bo = b*128 + o;
  const float inv = 1.0f/32768.0f;
  float mu_ = gp1[bo]*inv;
  float rs_ = rsqrtf(gp2[bo]*inv - mu_*mu_ + 1e-5f);
  float v = fmaxf((mraw - mu_)*rs_, 0.f);   // == max_k relu(norm(h_k)) exactly
  mv[o] = v;
  __syncthreads();
  if (o<3){
    float acc = ldin(fc_b, o, f32);
    for(int c=0;c<128;c++) acc = fmaf(ldin(fc_w, (size_t)o*128+c, f32), mv[c], acc);
    size_t oi = ((size_t)b*3 + o)*NS + s;
    if (f32) ((float*)outv)[oi] = acc;
    else     ((unsigned short*)outv)[oi] = f2bf(acc);
  }
}

// ---------------------------------------------------------------------------
extern "C" void kernel_launch(void* const* d_in, const int* in_sizes, int n_in,
                              void* d_out, int out_size, void* d_ws, size_t ws_size,
                              hipStream_t stream){
  const void* pc1   = d_in[0];
  const void* feats = d_in[1];
  const void* W1    = d_in[2];
  const void* W2    = d_in[4];
  const void* W3    = d_in[6];
  const void* fcw   = d_in[8];
  const void* fcb   = d_in[9];
  char* ws = (char*)d_ws;
  int*      fps  = (int*)     (ws + 0);          // 32768 B   (sentinel -1)
  float*    nxyz = (float*)   (ws + 32768);      // 98304 B
  int*      knn  = (int*)     (ws + 131072);     // 1048576 B
  float*    st   = (float*)   (ws + 1179648);    // 6*1024*4 = 24576 B  [s1a s2a s1b s2b s1c s2c]
  _Float16* Ha   = (_Float16*)(ws + 1204224);    // 67108864 B
  _Float16* Hb   = (_Float16*)(ws + 68313088);   // 67108864 B (total 135421952)
  _Float16* G    = Hb;  // G (8.9 MB) aliases Hb: read only by conv1, Hb first written by conv2

  // sentinel-fill fps_out (-1) so workers can spin on flag==data
  (void)hipMemsetAsync(fps, 0xFF, NB*NS*sizeof(int), stream);

  fps_knn_fused<<<8 + NWORK, 512, 0, stream>>>(pc1, feats, fps, G, st, nxyz, knn);

  conv_mfma<1><<<NM/128, 256, 0, stream>>>(pc1, G, knn, nxyz,
      (const _Float16*)nullptr, (const float*)nullptr, (const float*)nullptr,
      W1, Ha, st, st+1024);
  conv_mfma<2><<<NM/128, 256, 0, stream>>>(pc1, G, knn, nxyz,
      Ha, st, st+1024, W2, Hb, st+2048, st+3072);
  // conv3 writes M = per-center max (2 MB) into Ha head
  conv_mfma<3><<<NM/128, 256, 0, stream>>>(pc1, G, knn, nxyz,
      Hb, st+2048, st+3072, W3, Ha, st+4096, st+5120);

  final_kernel<<<NB*NS, 128, 0, stream>>>(pc1, Ha, st+4096, st+5120, fcw, fcb, d_out);
}

// Round 12
// 921.635 us; speedup vs baseline: 1.0565x; 1.0565x over previous
//
#include <hip/hip_runtime.h>
#include <hip/hip_fp16.h>

#define NB 8
#define NPTS 4096
#define NS 1024
#define NK 32
#define NM (NB*NS*NK)   // 262144 grouped points
#define NWORK 504       // fused worker blocks (grid = 8 + NWORK = 512 <= guaranteed residency)

typedef _Float16 f16x8 __attribute__((ext_vector_type(8)));
typedef float    f32x4 __attribute__((ext_vector_type(4)));
typedef float    f32x2 __attribute__((ext_vector_type(2)));

__device__ __forceinline__ float bf2f(unsigned short u){ return __uint_as_float(((unsigned)u)<<16); }
__device__ __forceinline__ unsigned short f2bf(float f){
  unsigned u = __float_as_uint(f);
  u = u + 0x7fffu + ((u>>16)&1u);   // RNE
  return (unsigned short)(u>>16);
}
__device__ __forceinline__ unsigned long long umax64(unsigned long long a, unsigned long long b){ return a>b?a:b; }

// ---- DPP wave64 reduce: row_shr 1/2/4/8 + row_bcast 15/31, result in lane 63.
#define DPP_STEP_MAX(x, ctrl, rm) { \
  unsigned _t = (unsigned)__builtin_amdgcn_update_dpp((int)(x), (int)(x), (ctrl), (rm), 0xf, false); \
  (x) = ((x) > _t) ? (x) : _t; }

__device__ __forceinline__ unsigned wave_max_u32(unsigned x){
  DPP_STEP_MAX(x, 0x111, 0xf);
  DPP_STEP_MAX(x, 0x112, 0xf);
  DPP_STEP_MAX(x, 0x114, 0xf);
  DPP_STEP_MAX(x, 0x118, 0xf);
  DPP_STEP_MAX(x, 0x142, 0xa);
  DPP_STEP_MAX(x, 0x143, 0xc);
  return (unsigned)__builtin_amdgcn_readlane((int)x, 63);
}

// Runtime dtype detection (block-uniform scalar branch): f32 data read as bf16
// halves decodes huge/denormal or exact-zero; true bf16 N(0,1) does not.
__device__ __forceinline__ bool detect_f32(const unsigned short* __restrict__ u){
  int huge_=0, zero_=0;
  #pragma unroll
  for (int i=0;i<64;i++){
    unsigned short w = u[i];
    if ((w & 0x7fffu) == 0) { zero_++; continue; }
    float a = fabsf(bf2f(w));
    if (a > 1e6f || a < 1e-6f) huge_++;
  }
  return (huge_ >= 8) || (zero_ >= 24);
}
__device__ __forceinline__ float ldin(const void* p, size_t i, bool f32){
  if (f32) return ((const float*)p)[i];
  else     return bf2f(((const unsigned short*)p)[i]);
}

// ---------------------------------------------------------------------------
// Fused FPS + feat_transpose + kNN (producer-consumer, one launch).
// VERBATIM R10 (550 us verified). FPS parked: chain is per-SIMD-issue +
// LDS-latency + barrier bound (R7 vmcnt null, R9 coord-bcast -260us,
// R11 8-wave -55us: VALU issue is per-SIMD so widening gains nothing).
// ---------------------------------------------------------------------------
__global__ __launch_bounds__(256, 2) void fps_knn_fused(
    const void* __restrict__ pc1,
    const void* __restrict__ feats,
    int* __restrict__ fps_out,
    _Float16* __restrict__ G,
    float* __restrict__ statz,
    float* __restrict__ new_xyz,
    int* __restrict__ knn_idx)
{
  __shared__ __align__(16) char smem[65600];
  int t = threadIdx.x;
  const bool f32 = detect_f32((const unsigned short*)pc1);
  if (blockIdx.x < 8){
    __builtin_amdgcn_s_setprio(1);     // FPS is the global critical path
    float4* cp4 = (float4*)smem;
    unsigned long long (*part)[4] = (unsigned long long (*)[4])(smem + 65536);
    int b = blockIdx.x;
    const size_t base = (size_t)b*3*NPTS;
    for (int i=t;i<NPTS;i+=256){
      float4 v;
      v.x = ldin(pc1, base+i, f32);
      v.y = ldin(pc1, base+NPTS+i, f32);
      v.z = ldin(pc1, base+2*NPTS+i, f32);
      v.w = 0.f;
      cp4[i] = v;
    }
    __syncthreads();
    f32x2 px[8],py[8],pz[8],dist[8];
    #pragma unroll
    for (int j=0;j<8;j++){
      float4 a = cp4[t*16+2*j], c = cp4[t*16+2*j+1];
      px[j] = f32x2{a.x, c.x};
      py[j] = f32x2{a.y, c.y};
      pz[j] = f32x2{a.z, c.z};
      dist[j] = f32x2{1e10f, 1e10f};
    }
    int far = 0;
    int w = t>>6, lane = t&63;
    for (int it=0; it<NS; it++){
      if (t==0)
        __hip_atomic_store(&fps_out[b*NS+it], far, __ATOMIC_RELAXED, __HIP_MEMORY_SCOPE_AGENT);
      float4 cc = cp4[far];
      f32x2 vcx = f32x2{cc.x,cc.x}, vcy = f32x2{cc.y,cc.y}, vcz = f32x2{cc.z,cc.z};
      {
        #pragma clang fp contract(off)
        #pragma unroll
        for (int j=0;j<8;j++){
          f32x2 dx = px[j]-vcx, dy = py[j]-vcy, dz = pz[j]-vcz;
          f32x2 d  = (dx*dx + dy*dy) + dz*dz;     // exact RN order: ((x2+y2)+z2)
          dist[j]  = __builtin_elementwise_min(dist[j], d);
        }
      }
      float d_[16];
      #pragma unroll
      for (int j=0;j<8;j++){ d_[2*j]=dist[j][0]; d_[2*j+1]=dist[j][1]; }
      float a0 = fmaxf(fmaxf(d_[0],d_[1]),d_[2]);      // -> v_max3_f32
      float a1 = fmaxf(fmaxf(d_[3],d_[4]),d_[5]);
      float a2 = fmaxf(fmaxf(d_[6],d_[7]),d_[8]);
      float a3 = fmaxf(fmaxf(d_[9],d_[10]),d_[11]);
      float a4 = fmaxf(fmaxf(d_[12],d_[13]),d_[14]);
      float b0 = fmaxf(fmaxf(a0,a1),a2);
      float b1 = fmaxf(fmaxf(a3,a4),d_[15]);
      float bl = fmaxf(b0,b1);
      int li = 0;
      #pragma unroll
      for (int i=15;i>=0;i--) if (d_[i]==bl) li = i;   // descending: final = lowest i
      unsigned blu = __float_as_uint(bl);               // dist>=0: bits monotone
      unsigned wm = wave_max_u32(blu);
      unsigned long long mk = __ballot(blu == wm);
      int l = __builtin_ctzll(mk);                      // lowest lane = lowest n
      int idx = __builtin_amdgcn_readlane(t*16+li, l);
      if (lane==0) part[it&1][w] = ((unsigned long long)wm<<32) | (unsigned)(NPTS-1-idx);
      __syncthreads();
      const ulonglong2* pp = (const ulonglong2*)&part[it&1][0];
      ulonglong2 A = pp[0], B = pp[1];
      unsigned long long m = umax64(umax64(A.x,A.y), umax64(B.x,B.y));
      far = NPTS-1 - (int)(m & 0xffffffffu);
    }
  } else {
    int wid = blockIdx.x - 8;
    // ---------------- phase 1: feats transpose -> G (grid-stride tiles) ----
    {
      float (*tile)[65] = (float (*)[65])smem;
      if (wid==0){
        for (int i=t;i<6144;i+=256) statz[i]=0.f;
      }
      for (int b2 = wid; b2 < 512; b2 += NWORK){
        int b = b2>>6, n0 = (b2&63)*64;
        #pragma unroll 4
        for (int i=0;i<32;i++){
          int idx = i*256 + t;
          int c = idx>>6, n = idx&63;
          tile[c][n] = ldin(feats, ((size_t)b*128 + c)*NPTS + n0 + n, f32);
        }
        __syncthreads();
        #pragma unroll 4
        for (int i=0;i<32;i++){
          int idx = i*256 + t;
          int n = idx>>7, c = idx&127;
          G[((size_t)b*NPTS + n0 + n)*136 + 3 + c] = (_Float16)tile[c][n];
        }
        if (t<64){
          size_t gb = ((size_t)b*NPTS + n0 + t)*136;
          G[gb]=(_Float16)0.f; G[gb+1]=(_Float16)0.f; G[gb+2]=(_Float16)0.f;
          #pragma unroll
          for (int c=131;c<136;c++) G[gb+c]=(_Float16)0.f;
        }
        __syncthreads();
      }
    }
    __syncthreads();
    // ---------------- phase 2: kNN centers (grid-stride, production order) -
    unsigned* hist            = (unsigned*)smem;                       // 16384 B
    unsigned long long* cand  = (unsigned long long*)(smem + 16384);   //  4096 B
    unsigned* partk           = (unsigned*)(smem + 20480);             //  1024 B
    unsigned* sup             = (unsigned*)(smem + 21504);             //    64 B
    unsigned* scal            = (unsigned*)(smem + 21568);             //     8 B
    int* sn0                  = (int*)(smem + 21576);
    for (int ci = wid; ci < NB*NS; ci += NWORK){
      int b = ci & 7, s = ci >> 3;          // consume in production order
      int blk = (b<<10) | s;
      if (t==0){
        int nv;
        while ((nv = __hip_atomic_load(&fps_out[b*NS+s], __ATOMIC_RELAXED,
                                       __HIP_MEMORY_SCOPE_AGENT)) == -1)
          __builtin_amdgcn_s_sleep(16);
        *sn0 = nv;
      }
      __syncthreads();
      const size_t base = (size_t)b*3*NPTS;
      int n0 = *sn0;
      float qx = ldin(pc1, base+n0, f32);
      float qy = ldin(pc1, base+NPTS+n0, f32);
      float qz = ldin(pc1, base+2*NPTS+n0, f32);
      if (t==0){
        new_xyz[(size_t)blk*3]=qx; new_xyz[(size_t)blk*3+1]=qy; new_xyz[(size_t)blk*3+2]=qz;
        scal[0]=0u;
      }
      #pragma unroll
      for (int j=0;j<16;j++) hist[j*256 + t] = 0u;
      float qn = __fadd_rn(__fadd_rn(__fmul_rn(qx,qx),__fmul_rn(qy,qy)),__fmul_rn(qz,qz));
      unsigned dv[16];
      #pragma unroll
      for (int k=0;k<16;k++){
        int n = t + 256*k;                               // coalesced global reads
        float x = ldin(pc1, base+n, f32);
        float y = ldin(pc1, base+NPTS+n, f32);
        float z = ldin(pc1, base+2*NPTS+n, f32);
        float pn = __fadd_rn(__fadd_rn(__fmul_rn(x,x),__fmul_rn(y,y)),__fmul_rn(z,z));
        float dt = __fadd_rn(__fadd_rn(__fmul_rn(qx,x),__fmul_rn(qy,y)),__fmul_rn(qz,z));
        float d  = __fsub_rn(__fadd_rn(qn,pn), __fmul_rn(2.f,dt));
        unsigned u = __float_as_uint(d);
        dv[k] = (u & 0x80000000u) ? ~u : (u | 0x80000000u);  // order-preserving map
      }
      __syncthreads();
      #pragma unroll
      for (int k=0;k<16;k++)
        atomicAdd(&hist[dv[k]>>20], 1u);
      __syncthreads();
      {
        unsigned ssum = 0;
        const uint4* hp = (const uint4*)&hist[t*16];
        #pragma unroll
        for (int j=0;j<4;j++){
          uint4 v = hp[j];
          ssum += v.x + v.y + v.z + v.w;
        }
        partk[t] = ssum;
      }
      __syncthreads();
      if (t < 16){
        unsigned qq = 0;
        #pragma unroll
        for (int j=0;j<16;j++) qq += partk[t*16 + j];
        sup[t] = qq;
      }
      __syncthreads();
      if (t == 0){
        unsigned acc = 0; int sb = 0;
        for (; sb < 16; sb++){ unsigned v = sup[sb]; if (acc + v >= NK) break; acc += v; }
        int pt = sb*16;
        for (; pt < sb*16+16; pt++){ unsigned v = partk[pt]; if (acc + v >= NK) break; acc += v; }
        int bn = pt*16;
        for (; bn < pt*16+16; bn++){ unsigned v = hist[bn]; if (acc + v >= NK) break; acc += v; }
        scal[1] = (unsigned)bn;
      }
      __syncthreads();
      unsigned beta = scal[1];
      #pragma unroll
      for (int k=0;k<16;k++){
        if ((dv[k]>>20) <= beta){
          unsigned pos = atomicAdd(&scal[0], 1u);
          if (pos < 512u)
            cand[pos] = ((unsigned long long)dv[k]<<32) | (unsigned)(t + 256*k);
        }
      }
      __syncthreads();
      int C = (int)scal[0]; if (C > 512) C = 512;
      for (int tt = t; tt < C; tt += 256){
        unsigned long long K = cand[tt];
        int rank = 0;
        for (int j = 0; j < C; j++) rank += (cand[j] < K) ? 1 : 0;   // broadcast reads
        if (rank < NK) knn_idx[(size_t)blk*NK + rank] = (int)(K & 0xffffffffu);
      }
      __syncthreads();   // smem reused next center
    }
  }
}

// ---------------------------------------------------------------------------
// MFMA conv. LAYER 1: R10-verbatim (wt LDS staging + barriers; K=131 ragged).
// LAYER 2/3: barrier-free K-loop (unroll 2, R10-verified) with R12 change:
// the Hin stage loop uses the C-write's fi-indexing (row=fi>>4,
// col=(fi&15)*8) so a wave's 64 lanes read 1 KB CONTIGUOUS global (was 16B
// per lane at 256B stride = 4x transaction inflation) and LDS writes drop
// from 8-way to ~4-way bank conflict. Element math unchanged -> bit-identical.
// LAYER 3 epilogue emits per-center max (R8 exact max-fold).
// ---------------------------------------------------------------------------
template<int LAYER>
__global__ __launch_bounds__(256)
__attribute__((amdgpu_waves_per_eu(1,3)))
void conv_mfma(
    const void* __restrict__ pc1,
    const _Float16* __restrict__ G,
    const int* __restrict__ knn_idx,
    const float* __restrict__ new_xyz,
    const _Float16* __restrict__ Hin,
    const float* __restrict__ gp1,
    const float* __restrict__ gp2,
    const void* __restrict__ W,
    _Float16* __restrict__ Hout,
    float* __restrict__ gs1, float* __restrict__ gs2)
{
  constexpr int KC  = (LAYER==1)?131:128;
  constexpr int KCP = (LAYER==1)?160:128;
  constexpr int HSW = (LAYER==1)?168:136;
  __shared__ __align__(16) _Float16 hs[128][HSW];
  __shared__ __align__(16) _Float16 wt[(LAYER==1)?128:1][40];
  __shared__ float red1[4][64], red2[4][64];
  __shared__ int   nidx[128];
  __shared__ float cxyz[4][3];
  __shared__ __align__(16) _Float16 smuh[128], srsh[128];
  int blk = blockIdx.x;
  int m0 = blk*128;
  int b  = m0 >> 15;
  int t  = threadIdx.x;
  const bool f32 = detect_f32((const unsigned short*)pc1);
  int w = t>>6, lane = t&63;
  int l16 = lane&15, q = lane>>4, q8 = q*8;
  int wr = (w&1)*64, wc = (w>>1)*64;

  if (LAYER==1){
    if (t<128) nidx[t] = knn_idx[m0+t];
    if (t<12)  cxyz[t/3][t%3] = new_xyz[(size_t)(m0>>5)*3 + t];
    __syncthreads();
    for (int u=t; u<128*17; u+=256){
      int p = u/17, qq = u - p*17;
      const f16x8* src = (const f16x8*)(G + ((size_t)b*NPTS + nidx[p])*136 + qq*8);
      *(f16x8*)&hs[p][qq*8] = *src;
    }
    for (int u=t; u<128*3; u+=256){
      int p = u/3, qq = u - p*3;
      uint4 z; z.x=z.y=z.z=z.w=0u;
      *(uint4*)&hs[p][136+qq*8] = z;
    }
    __syncthreads();
    if (t<128){
      int n = nidx[t];
      float cx = cxyz[t>>5][0], cy = cxyz[t>>5][1], cz = cxyz[t>>5][2];
      hs[t][0] = (_Float16)(ldin(pc1, ((size_t)b*3+0)*NPTS+n, f32) - cx);
      hs[t][1] = (_Float16)(ldin(pc1, ((size_t)b*3+1)*NPTS+n, f32) - cy);
      hs[t][2] = (_Float16)(ldin(pc1, ((size_t)b*3+2)*NPTS+n, f32) - cz);
    }
    __syncthreads();
  } else {
    if (t<128){
      const float inv = 1.0f/32768.0f;
      float m = gp1[b*128+t]*inv;
      smuh[t] = (_Float16)m;
      srsh[t] = (_Float16)rsqrtf(gp2[b*128+t]*inv - m*m + 1e-5f);
    }
    __syncthreads();
    // R12: coalesced stage — fi-indexing, 1 KB contiguous per wave-instr.
    f16x8 zero8 = {};
    #pragma unroll
    for (int j=0;j<8;j++){
      int fi = j*256 + t;
      int row = fi >> 4, col = (fi & 15)*8;
      f16x8 v   = *(const f16x8*)(Hin + (size_t)(m0+row)*128 + col);
      f16x8 mu8 = *(const f16x8*)&smuh[col];
      f16x8 rs8 = *(const f16x8*)&srsh[col];
      f16x8 o = (v - mu8) * rs8;                    // v_pk_*_f16
      o = __builtin_elementwise_max(o, zero8);      // relu
      *(f16x8*)&hs[row][col] = o;
    }
    __syncthreads();
  }

  f32x4 acc[4][4];
  #pragma unroll
  for (int i=0;i<4;i++)
    #pragma unroll
    for (int c=0;c<4;c++){ acc[i][c][0]=0.f; acc[i][c][1]=0.f; acc[i][c][2]=0.f; acc[i][c][3]=0.f; }

  if (LAYER==1){
    for (int k0=0; k0<KCP; k0+=32){
      {
        int o = t>>1, half = t&1;
        f16x8 w0, w1;
        #pragma unroll
        for (int jj=0;jj<8;jj++){
          int c0 = k0 + half*16 + jj, c1 = c0 + 8;
          w0[jj] = (_Float16)((c0<KC) ? ldin(W, (size_t)o*KC + c0, f32) : 0.f);
          w1[jj] = (_Float16)((c1<KC) ? ldin(W, (size_t)o*KC + c1, f32) : 0.f);
        }
        *(f16x8*)&wt[o][half*16]     = w0;
        *(f16x8*)&wt[o][half*16 + 8] = w1;
      }
      __syncthreads();
      f16x8 av[4], bv[4];
      #pragma unroll
      for (int i=0;i<4;i++) av[i] = *(const f16x8*)&hs[wr + i*16 + l16][k0 + q8];
      #pragma unroll
      for (int c=0;c<4;c++) bv[c] = *(const f16x8*)&wt[wc + c*16 + l16][q8];
      #pragma unroll
      for (int i=0;i<4;i++)
        #pragma unroll
        for (int c=0;c<4;c++)
          acc[i][c] = __builtin_amdgcn_mfma_f32_16x16x32_f16(av[i], bv[c], acc[i][c], 0,0,0);
      __syncthreads();
    }
  } else {
    // barrier-free K-loop: B-frags direct from global (L2-hot), A from LDS.
    // unroll 2 — halves in-flight loads / VGPR pressure.
    #pragma unroll 2
    for (int k0=0; k0<128; k0+=32){
      f16x8 av[4], bv[4];
      #pragma unroll
      for (int i=0;i<4;i++) av[i] = *(const f16x8*)&hs[wr + i*16 + l16][k0 + q8];
      #pragma unroll
      for (int c=0;c<4;c++){
        int row = wc + c*16 + l16;
        if (f32){
          const f32x4* Wr = (const f32x4*)((const float*)W + (size_t)row*128 + k0 + q8);
          f32x4 v0 = Wr[0], v1 = Wr[1];
          f16x8 bb;
          bb[0]=(_Float16)v0[0]; bb[1]=(_Float16)v0[1]; bb[2]=(_Float16)v0[2]; bb[3]=(_Float16)v0[3];
          bb[4]=(_Float16)v1[0]; bb[5]=(_Float16)v1[1]; bb[6]=(_Float16)v1[2]; bb[7]=(_Float16)v1[3];
          bv[c] = bb;
        } else {
          const ushort4* Wr = (const ushort4*)((const unsigned short*)W + (size_t)row*128 + k0 + q8);
          ushort4 u0 = Wr[0], u1 = Wr[1];
          f16x8 bb;
          bb[0]=(_Float16)bf2f(u0.x); bb[1]=(_Float16)bf2f(u0.y); bb[2]=(_Float16)bf2f(u0.z); bb[3]=(_Float16)bf2f(u0.w);
          bb[4]=(_Float16)bf2f(u1.x); bb[5]=(_Float16)bf2f(u1.y); bb[6]=(_Float16)bf2f(u1.z); bb[7]=(_Float16)bf2f(u1.w);
          bv[c] = bb;
        }
      }
      #pragma unroll
      for (int i=0;i<4;i++)
        #pragma unroll
        for (int c=0;c<4;c++)
          acc[i][c] = __builtin_amdgcn_mfma_f32_16x16x32_f16(av[i], bv[c], acc[i][c], 0,0,0);
    }
    __syncthreads();   // all waves done reading hs before epilogue overwrites
  }

  // epilogue: stats from f32 acc + C -> hs (f16) -> global
  #pragma unroll
  for (int c=0;c<4;c++){
    int o = wc + c*16 + l16;
    float s1=0.f, s2=0.f;
    #pragma unroll
    for (int i=0;i<4;i++){
      int row = wr + i*16 + q*4;
      #pragma unroll
      for (int r=0;r<4;r++){
        float v = acc[i][c][r];
        hs[row + r][o] = (_Float16)v;
        s1 += v; s2 = fmaf(v,v,s2);
      }
    }
    s1 += __shfl_xor(s1, 16, 64); s1 += __shfl_xor(s1, 32, 64);
    s2 += __shfl_xor(s2, 16, 64); s2 += __shfl_xor(s2, 32, 64);
    if (q==0){ red1[w][c*16+l16] = s1; red2[w][c*16+l16] = s2; }
  }
  __syncthreads();
  if (LAYER==3){
    // per-center max over the 32 neighbor rows -> M[center][c] (f16).
    if (t<128){
      #pragma unroll
      for (int c4=0;c4<4;c4++){
        _Float16 mx = hs[c4*32][t];
        #pragma unroll
        for (int r=1;r<32;r++){
          _Float16 v = hs[c4*32 + r][t];
          mx = (v > mx) ? v : mx;
        }
        Hout[(size_t)(blk*4 + c4)*128 + t] = mx;   // 256B coalesced per c4
      }
    }
  } else {
    _Float16* dst0 = Hout + (size_t)m0*128;
    #pragma unroll
    for (int j=0;j<8;j++){
      int fi = j*256 + t;
      int row = fi >> 4, col = (fi & 15)*8;
      *(f16x8*)(dst0 + (size_t)fi*8) = *(const f16x8*)&hs[row][col];
    }
  }
  if (t<128){
    int lo = t & 63, g = (t>>6)*2;
    unsafeAtomicAdd(&gs1[b*128+t], red1[g][lo] + red1[g+1][lo]);
    unsafeAtomicAdd(&gs2[b*128+t], red2[g][lo] + red2[g+1][lo]);
  }
}

// ---------------------------------------------------------------------------
// Final (R8): M already holds max_k h (per center, 128 ch). Just norm+relu
// per channel, then fc 128->3. Reads 2 MB instead of 67 MB.
// ---------------------------------------------------------------------------
__global__ __launch_bounds__(128) void final_kernel(
    const void* __restrict__ pc1,
    const _Float16* __restrict__ M,
    const float* __restrict__ gp1, const float* __restrict__ gp2,
    const void* __restrict__ fc_w, const void* __restrict__ fc_b,
    void* __restrict__ outv)
{
  __shared__ float mv[128];
  int blk = blockIdx.x;       // b*1024+s
  int b = blk>>10, s = blk & 1023;
  int o = threadIdx.x;
  const bool f32 = detect_f32((const unsigned short*)pc1);
  float mraw = (float)M[(size_t)blk*128 + o];   // exact f16->f32
  int bo = b*128 + o;
  const float inv = 1.0f/32768.0f;
  float mu_ = gp1[bo]*inv;
  float rs_ = rsqrtf(gp2[bo]*inv - mu_*mu_ + 1e-5f);
  float v = fmaxf((mraw - mu_)*rs_, 0.f);   // == max_k relu(norm(h_k)) exactly
  mv[o] = v;
  __syncthreads();
  if (o<3){
    float acc = ldin(fc_b, o, f32);
    for(int c=0;c<128;c++) acc = fmaf(ldin(fc_w, (size_t)o*128+c, f32), mv[c], acc);
    size_t oi = ((size_t)b*3 + o)*NS + s;
    if (f32) ((float*)outv)[oi] = acc;
    else     ((unsigned short*)outv)[oi] = f2bf(acc);
  }
}

// ---------------------------------------------------------------------------
extern "C" void kernel_launch(void* const* d_in, const int* in_sizes, int n_in,
                              void* d_out, int out_size, void* d_ws, size_t ws_size,
                              hipStream_t stream){
  const void* pc1   = d_in[0];
  const void* feats = d_in[1];
  const void* W1    = d_in[2];
  const void* W2    = d_in[4];
  const void* W3    = d_in[6];
  const void* fcw   = d_in[8];
  const void* fcb   = d_in[9];
  char* ws = (char*)d_ws;
  int*      fps  = (int*)     (ws + 0);          // 32768 B   (sentinel -1)
  float*    nxyz = (float*)   (ws + 32768);      // 98304 B
  int*      knn  = (int*)     (ws + 131072);     // 1048576 B
  float*    st   = (float*)   (ws + 1179648);    // 6*1024*4 = 24576 B  [s1a s2a s1b s2b s1c s2c]
  _Float16* Ha   = (_Float16*)(ws + 1204224);    // 67108864 B
  _Float16* Hb   = (_Float16*)(ws + 68313088);   // 67108864 B (total 135421952)
  _Float16* G    = Hb;  // G (8.9 MB) aliases Hb: read only by conv1, Hb first written by conv2

  // sentinel-fill fps_out (-1) so workers can spin on flag==data
  (void)hipMemsetAsync(fps, 0xFF, NB*NS*sizeof(int), stream);

  fps_knn_fused<<<8 + NWORK, 256, 0, stream>>>(pc1, feats, fps, G, st, nxyz, knn);

  conv_mfma<1><<<NM/128, 256, 0, stream>>>(pc1, G, knn, nxyz,
      (const _Float16*)nullptr, (const float*)nullptr, (const float*)nullptr,
      W1, Ha, st, st+1024);
  conv_mfma<2><<<NM/128, 256, 0, stream>>>(pc1, G, knn, nxyz,
      Ha, st, st+1024, W2, Hb, st+2048, st+3072);
  // conv3 writes M = per-center max (2 MB) into Ha head
  conv_mfma<3><<<NM/128, 256, 0, stream>>>(pc1, G, knn, nxyz,
      Hb, st+2048, st+3072, W3, Ha, st+4096, st+5120);

  final_kernel<<<NB*NS, 128, 0, stream>>>(pc1, Ha, st+4096, st+5120, fcw, fcb, d_out);
}

// Round 13
// 881.564 us; speedup vs baseline: 1.1046x; 1.0455x over previous
//
#include <hip/hip_runtime.h>
#include <hip/hip_fp16.h>

#define NB 8
#define NPTS 4096
#define NS 1024
#define NK 32
#define NM (NB*NS*NK)   // 262144 grouped points
#define NWORK 504       // fused worker blocks (grid = 8 + NWORK = 512 <= guaranteed residency)

typedef _Float16 f16x8 __attribute__((ext_vector_type(8)));
typedef float    f32x4 __attribute__((ext_vector_type(4)));
typedef float    f32x2 __attribute__((ext_vector_type(2)));

__device__ __forceinline__ float bf2f(unsigned short u){ return __uint_as_float(((unsigned)u)<<16); }
__device__ __forceinline__ unsigned short f2bf(float f){
  unsigned u = __float_as_uint(f);
  u = u + 0x7fffu + ((u>>16)&1u);   // RNE
  return (unsigned short)(u>>16);
}
__device__ __forceinline__ unsigned long long umax64(unsigned long long a, unsigned long long b){ return a>b?a:b; }

// ---- DPP wave64 reduce: row_shr 1/2/4/8 + row_bcast 15/31, result in lane 63.
#define DPP_STEP_MAX(x, ctrl, rm) { \
  unsigned _t = (unsigned)__builtin_amdgcn_update_dpp((int)(x), (int)(x), (ctrl), (rm), 0xf, false); \
  (x) = ((x) > _t) ? (x) : _t; }

__device__ __forceinline__ unsigned wave_max_u32(unsigned x){
  DPP_STEP_MAX(x, 0x111, 0xf);
  DPP_STEP_MAX(x, 0x112, 0xf);
  DPP_STEP_MAX(x, 0x114, 0xf);
  DPP_STEP_MAX(x, 0x118, 0xf);
  DPP_STEP_MAX(x, 0x142, 0xa);
  DPP_STEP_MAX(x, 0x143, 0xc);
  return (unsigned)__builtin_amdgcn_readlane((int)x, 63);
}

// Runtime dtype detection (block-uniform scalar branch): f32 data read as bf16
// halves decodes huge/denormal or exact-zero; true bf16 N(0,1) does not.
__device__ __forceinline__ bool detect_f32(const unsigned short* __restrict__ u){
  int huge_=0, zero_=0;
  #pragma unroll
  for (int i=0;i<64;i++){
    unsigned short w = u[i];
    if ((w & 0x7fffu) == 0) { zero_++; continue; }
    float a = fabsf(bf2f(w));
    if (a > 1e6f || a < 1e-6f) huge_++;
  }
  return (huge_ >= 8) || (zero_ >= 24);
}
__device__ __forceinline__ float ldin(const void* p, size_t i, bool f32){
  if (f32) return ((const float*)p)[i];
  else     return bf2f(((const unsigned short*)p)[i]);
}

// ---------------------------------------------------------------------------
// Fused FPS + feat_transpose + W1-pad + kNN (producer-consumer, one launch).
// FPS path VERBATIM R10 (551 us verified; parked — per-SIMD-issue/LDS/barrier
// bound). R13: worker block 0 additionally pads W1 [128x131] -> W1p [128][160]
// f16 (RNE convert identical to conv1's old wt staging; zero pad >=131) so
// conv1 can use the barrier-free K-loop. W1p handoff is kernel-boundary bulk
// (same proven class as G).
// ---------------------------------------------------------------------------
__global__ __launch_bounds__(256, 2) void fps_knn_fused(
    const void* __restrict__ pc1,
    const void* __restrict__ feats,
    const void* __restrict__ W1,
    int* __restrict__ fps_out,
    _Float16* __restrict__ G,
    _Float16* __restrict__ W1p,
    float* __restrict__ statz,
    float* __restrict__ new_xyz,
    int* __restrict__ knn_idx)
{
  __shared__ __align__(16) char smem[65600];
  int t = threadIdx.x;
  const bool f32 = detect_f32((const unsigned short*)pc1);
  if (blockIdx.x < 8){
    __builtin_amdgcn_s_setprio(1);     // FPS is the global critical path
    float4* cp4 = (float4*)smem;
    unsigned long long (*part)[4] = (unsigned long long (*)[4])(smem + 65536);
    int b = blockIdx.x;
    const size_t base = (size_t)b*3*NPTS;
    for (int i=t;i<NPTS;i+=256){
      float4 v;
      v.x = ldin(pc1, base+i, f32);
      v.y = ldin(pc1, base+NPTS+i, f32);
      v.z = ldin(pc1, base+2*NPTS+i, f32);
      v.w = 0.f;
      cp4[i] = v;
    }
    __syncthreads();
    f32x2 px[8],py[8],pz[8],dist[8];
    #pragma unroll
    for (int j=0;j<8;j++){
      float4 a = cp4[t*16+2*j], c = cp4[t*16+2*j+1];
      px[j] = f32x2{a.x, c.x};
      py[j] = f32x2{a.y, c.y};
      pz[j] = f32x2{a.z, c.z};
      dist[j] = f32x2{1e10f, 1e10f};
    }
    int far = 0;
    int w = t>>6, lane = t&63;
    for (int it=0; it<NS; it++){
      if (t==0)
        __hip_atomic_store(&fps_out[b*NS+it], far, __ATOMIC_RELAXED, __HIP_MEMORY_SCOPE_AGENT);
      float4 cc = cp4[far];
      f32x2 vcx = f32x2{cc.x,cc.x}, vcy = f32x2{cc.y,cc.y}, vcz = f32x2{cc.z,cc.z};
      {
        #pragma clang fp contract(off)
        #pragma unroll
        for (int j=0;j<8;j++){
          f32x2 dx = px[j]-vcx, dy = py[j]-vcy, dz = pz[j]-vcz;
          f32x2 d  = (dx*dx + dy*dy) + dz*dz;     // exact RN order: ((x2+y2)+z2)
          dist[j]  = __builtin_elementwise_min(dist[j], d);
        }
      }
      float d_[16];
      #pragma unroll
      for (int j=0;j<8;j++){ d_[2*j]=dist[j][0]; d_[2*j+1]=dist[j][1]; }
      float a0 = fmaxf(fmaxf(d_[0],d_[1]),d_[2]);      // -> v_max3_f32
      float a1 = fmaxf(fmaxf(d_[3],d_[4]),d_[5]);
      float a2 = fmaxf(fmaxf(d_[6],d_[7]),d_[8]);
      float a3 = fmaxf(fmaxf(d_[9],d_[10]),d_[11]);
      float a4 = fmaxf(fmaxf(d_[12],d_[13]),d_[14]);
      float b0 = fmaxf(fmaxf(a0,a1),a2);
      float b1 = fmaxf(fmaxf(a3,a4),d_[15]);
      float bl = fmaxf(b0,b1);
      int li = 0;
      #pragma unroll
      for (int i=15;i>=0;i--) if (d_[i]==bl) li = i;   // descending: final = lowest i
      unsigned blu = __float_as_uint(bl);               // dist>=0: bits monotone
      unsigned wm = wave_max_u32(blu);
      unsigned long long mk = __ballot(blu == wm);
      int l = __builtin_ctzll(mk);                      // lowest lane = lowest n
      int idx = __builtin_amdgcn_readlane(t*16+li, l);
      if (lane==0) part[it&1][w] = ((unsigned long long)wm<<32) | (unsigned)(NPTS-1-idx);
      __syncthreads();
      const ulonglong2* pp = (const ulonglong2*)&part[it&1][0];
      ulonglong2 A = pp[0], B = pp[1];
      unsigned long long m = umax64(umax64(A.x,A.y), umax64(B.x,B.y));
      far = NPTS-1 - (int)(m & 0xffffffffu);
    }
  } else {
    int wid = blockIdx.x - 8;
    // ---------------- phase 1: feats transpose -> G (grid-stride tiles) ----
    {
      float (*tile)[65] = (float (*)[65])smem;
      if (wid==0){
        for (int i=t;i<6144;i+=256) statz[i]=0.f;
        // R13: pad W1 [128x131] -> W1p [128][160] f16 (RNE; zero pad).
        for (int i=t;i<128*160;i+=256){
          int r = i/160, c = i - r*160;
          W1p[i] = (c<131) ? (_Float16)ldin(W1, (size_t)r*131 + c, f32) : (_Float16)0.f;
        }
      }
      for (int b2 = wid; b2 < 512; b2 += NWORK){
        int b = b2>>6, n0 = (b2&63)*64;
        #pragma unroll 4
        for (int i=0;i<32;i++){
          int idx = i*256 + t;
          int c = idx>>6, n = idx&63;
          tile[c][n] = ldin(feats, ((size_t)b*128 + c)*NPTS + n0 + n, f32);
        }
        __syncthreads();
        #pragma unroll 4
        for (int i=0;i<32;i++){
          int idx = i*256 + t;
          int n = idx>>7, c = idx&127;
          G[((size_t)b*NPTS + n0 + n)*136 + 3 + c] = (_Float16)tile[c][n];
        }
        if (t<64){
          size_t gb = ((size_t)b*NPTS + n0 + t)*136;
          G[gb]=(_Float16)0.f; G[gb+1]=(_Float16)0.f; G[gb+2]=(_Float16)0.f;
          #pragma unroll
          for (int c=131;c<136;c++) G[gb+c]=(_Float16)0.f;
        }
        __syncthreads();
      }
    }
    __syncthreads();
    // ---------------- phase 2: kNN centers (grid-stride, production order) -
    unsigned* hist            = (unsigned*)smem;                       // 16384 B
    unsigned long long* cand  = (unsigned long long*)(smem + 16384);   //  4096 B
    unsigned* partk           = (unsigned*)(smem + 20480);             //  1024 B
    unsigned* sup             = (unsigned*)(smem + 21504);             //    64 B
    unsigned* scal            = (unsigned*)(smem + 21568);             //     8 B
    int* sn0                  = (int*)(smem + 21576);
    for (int ci = wid; ci < NB*NS; ci += NWORK){
      int b = ci & 7, s = ci >> 3;          // consume in production order
      int blk = (b<<10) | s;
      if (t==0){
        int nv;
        while ((nv = __hip_atomic_load(&fps_out[b*NS+s], __ATOMIC_RELAXED,
                                       __HIP_MEMORY_SCOPE_AGENT)) == -1)
          __builtin_amdgcn_s_sleep(16);
        *sn0 = nv;
      }
      __syncthreads();
      const size_t base = (size_t)b*3*NPTS;
      int n0 = *sn0;
      float qx = ldin(pc1, base+n0, f32);
      float qy = ldin(pc1, base+NPTS+n0, f32);
      float qz = ldin(pc1, base+2*NPTS+n0, f32);
      if (t==0){
        new_xyz[(size_t)blk*3]=qx; new_xyz[(size_t)blk*3+1]=qy; new_xyz[(size_t)blk*3+2]=qz;
        scal[0]=0u;
      }
      #pragma unroll
      for (int j=0;j<16;j++) hist[j*256 + t] = 0u;
      float qn = __fadd_rn(__fadd_rn(__fmul_rn(qx,qx),__fmul_rn(qy,qy)),__fmul_rn(qz,qz));
      unsigned dv[16];
      #pragma unroll
      for (int k=0;k<16;k++){
        int n = t + 256*k;                               // coalesced global reads
        float x = ldin(pc1, base+n, f32);
        float y = ldin(pc1, base+NPTS+n, f32);
        float z = ldin(pc1, base+2*NPTS+n, f32);
        float pn = __fadd_rn(__fadd_rn(__fmul_rn(x,x),__fmul_rn(y,y)),__fmul_rn(z,z));
        float dt = __fadd_rn(__fadd_rn(__fmul_rn(qx,x),__fmul_rn(qy,y)),__fmul_rn(qz,z));
        float d  = __fsub_rn(__fadd_rn(qn,pn), __fmul_rn(2.f,dt));
        unsigned u = __float_as_uint(d);
        dv[k] = (u & 0x80000000u) ? ~u : (u | 0x80000000u);  // order-preserving map
      }
      __syncthreads();
      #pragma unroll
      for (int k=0;k<16;k++)
        atomicAdd(&hist[dv[k]>>20], 1u);
      __syncthreads();
      {
        unsigned ssum = 0;
        const uint4* hp = (const uint4*)&hist[t*16];
        #pragma unroll
        for (int j=0;j<4;j++){
          uint4 v = hp[j];
          ssum += v.x + v.y + v.z + v.w;
        }
        partk[t] = ssum;
      }
      __syncthreads();
      if (t < 16){
        unsigned qq = 0;
        #pragma unroll
        for (int j=0;j<16;j++) qq += partk[t*16 + j];
        sup[t] = qq;
      }
      __syncthreads();
      if (t == 0){
        unsigned acc = 0; int sb = 0;
        for (; sb < 16; sb++){ unsigned v = sup[sb]; if (acc + v >= NK) break; acc += v; }
        int pt = sb*16;
        for (; pt < sb*16+16; pt++){ unsigned v = partk[pt]; if (acc + v >= NK) break; acc += v; }
        int bn = pt*16;
        for (; bn < pt*16+16; bn++){ unsigned v = hist[bn]; if (acc + v >= NK) break; acc += v; }
        scal[1] = (unsigned)bn;
      }
      __syncthreads();
      unsigned beta = scal[1];
      #pragma unroll
      for (int k=0;k<16;k++){
        if ((dv[k]>>20) <= beta){
          unsigned pos = atomicAdd(&scal[0], 1u);
          if (pos < 512u)
            cand[pos] = ((unsigned long long)dv[k]<<32) | (unsigned)(t + 256*k);
        }
      }
      __syncthreads();
      int C = (int)scal[0]; if (C > 512) C = 512;
      for (int tt = t; tt < C; tt += 256){
        unsigned long long K = cand[tt];
        int rank = 0;
        for (int j = 0; j < C; j++) rank += (cand[j] < K) ? 1 : 0;   // broadcast reads
        if (rank < NK) knn_idx[(size_t)blk*NK + rank] = (int)(K & 0xffffffffu);
      }
      __syncthreads();   // smem reused next center
    }
  }
}

// ---------------------------------------------------------------------------
// MFMA conv. R13: ALL layers now use the barrier-free K-loop (unroll 2).
// LAYER 1: B-frags from pre-padded W1p [128][160] f16 (aligned f16x8 loads;
// values bit-identical to the old wt staging; hs cols 131..159 zeroed so
// pad products are exactly 0 and acc update order is unchanged).
// LAYER 2/3: B-frags direct from global W2/W3 (L2-hot) with RNE convert.
// R12 coalesced Hin stage kept. LAYER 3 epilogue: per-center max (R8 fold).
// ---------------------------------------------------------------------------
template<int LAYER>
__global__ __launch_bounds__(256)
__attribute__((amdgpu_waves_per_eu(1,3)))
void conv_mfma(
    const void* __restrict__ pc1,
    const _Float16* __restrict__ G,
    const int* __restrict__ knn_idx,
    const float* __restrict__ new_xyz,
    const _Float16* __restrict__ Hin,
    const float* __restrict__ gp1,
    const float* __restrict__ gp2,
    const void* __restrict__ W,
    _Float16* __restrict__ Hout,
    float* __restrict__ gs1, float* __restrict__ gs2)
{
  constexpr int KCP = (LAYER==1)?160:128;
  constexpr int HSW = (LAYER==1)?168:136;
  __shared__ __align__(16) _Float16 hs[128][HSW];
  __shared__ float red1[4][64], red2[4][64];
  __shared__ int   nidx[128];
  __shared__ float cxyz[4][3];
  __shared__ __align__(16) _Float16 smuh[128], srsh[128];
  int blk = blockIdx.x;
  int m0 = blk*128;
  int b  = m0 >> 15;
  int t  = threadIdx.x;
  const bool f32 = detect_f32((const unsigned short*)pc1);
  int w = t>>6, lane = t&63;
  int l16 = lane&15, q = lane>>4, q8 = q*8;
  int wr = (w&1)*64, wc = (w>>1)*64;

  if (LAYER==1){
    if (t<128) nidx[t] = knn_idx[m0+t];
    if (t<12)  cxyz[t/3][t%3] = new_xyz[(size_t)(m0>>5)*3 + t];
    __syncthreads();
    for (int u=t; u<128*17; u+=256){
      int p = u/17, qq = u - p*17;
      const f16x8* src = (const f16x8*)(G + ((size_t)b*NPTS + nidx[p])*136 + qq*8);
      *(f16x8*)&hs[p][qq*8] = *src;
    }
    for (int u=t; u<128*3; u+=256){
      int p = u/3, qq = u - p*3;
      uint4 z; z.x=z.y=z.z=z.w=0u;
      *(uint4*)&hs[p][136+qq*8] = z;
    }
    __syncthreads();
    if (t<128){
      int n = nidx[t];
      float cx = cxyz[t>>5][0], cy = cxyz[t>>5][1], cz = cxyz[t>>5][2];
      hs[t][0] = (_Float16)(ldin(pc1, ((size_t)b*3+0)*NPTS+n, f32) - cx);
      hs[t][1] = (_Float16)(ldin(pc1, ((size_t)b*3+1)*NPTS+n, f32) - cy);
      hs[t][2] = (_Float16)(ldin(pc1, ((size_t)b*3+2)*NPTS+n, f32) - cz);
    }
    __syncthreads();
  } else {
    if (t<128){
      const float inv = 1.0f/32768.0f;
      float m = gp1[b*128+t]*inv;
      smuh[t] = (_Float16)m;
      srsh[t] = (_Float16)rsqrtf(gp2[b*128+t]*inv - m*m + 1e-5f);
    }
    __syncthreads();
    // coalesced stage — fi-indexing, 1 KB contiguous per wave-instr.
    f16x8 zero8 = {};
    #pragma unroll
    for (int j=0;j<8;j++){
      int fi = j*256 + t;
      int row = fi >> 4, col = (fi & 15)*8;
      f16x8 v   = *(const f16x8*)(Hin + (size_t)(m0+row)*128 + col);
      f16x8 mu8 = *(const f16x8*)&smuh[col];
      f16x8 rs8 = *(const f16x8*)&srsh[col];
      f16x8 o = (v - mu8) * rs8;                    // v_pk_*_f16
      o = __builtin_elementwise_max(o, zero8);      // relu
      *(f16x8*)&hs[row][col] = o;
    }
    __syncthreads();
  }

  f32x4 acc[4][4];
  #pragma unroll
  for (int i=0;i<4;i++)
    #pragma unroll
    for (int c=0;c<4;c++){ acc[i][c][0]=0.f; acc[i][c][1]=0.f; acc[i][c][2]=0.f; acc[i][c][3]=0.f; }

  // barrier-free K-loop (all layers): A from LDS, B from global (L2-hot).
  #pragma unroll 2
  for (int k0=0; k0<KCP; k0+=32){
    f16x8 av[4], bv[4];
    #pragma unroll
    for (int i=0;i<4;i++) av[i] = *(const f16x8*)&hs[wr + i*16 + l16][k0 + q8];
    #pragma unroll
    for (int c=0;c<4;c++){
      int row = wc + c*16 + l16;
      if (LAYER==1){
        bv[c] = *(const f16x8*)((const _Float16*)W + (size_t)row*160 + k0 + q8);
      } else if (f32){
        const f32x4* Wr = (const f32x4*)((const float*)W + (size_t)row*128 + k0 + q8);
        f32x4 v0 = Wr[0], v1 = Wr[1];
        f16x8 bb;
        bb[0]=(_Float16)v0[0]; bb[1]=(_Float16)v0[1]; bb[2]=(_Float16)v0[2]; bb[3]=(_Float16)v0[3];
        bb[4]=(_Float16)v1[0]; bb[5]=(_Float16)v1[1]; bb[6]=(_Float16)v1[2]; bb[7]=(_Float16)v1[3];
        bv[c] = bb;
      } else {
        const ushort4* Wr = (const ushort4*)((const unsigned short*)W + (size_t)row*128 + k0 + q8);
        ushort4 u0 = Wr[0], u1 = Wr[1];
        f16x8 bb;
        bb[0]=(_Float16)bf2f(u0.x); bb[1]=(_Float16)bf2f(u0.y); bb[2]=(_Float16)bf2f(u0.z); bb[3]=(_Float16)bf2f(u0.w);
        bb[4]=(_Float16)bf2f(u1.x); bb[5]=(_Float16)bf2f(u1.y); bb[6]=(_Float16)bf2f(u1.z); bb[7]=(_Float16)bf2f(u1.w);
        bv[c] = bb;
      }
    }
    #pragma unroll
    for (int i=0;i<4;i++)
      #pragma unroll
      for (int c=0;c<4;c++)
        acc[i][c] = __builtin_amdgcn_mfma_f32_16x16x32_f16(av[i], bv[c], acc[i][c], 0,0,0);
  }
  __syncthreads();   // all waves done reading hs before epilogue overwrites

  // epilogue: stats from f32 acc + C -> hs (f16) -> global
  #pragma unroll
  for (int c=0;c<4;c++){
    int o = wc + c*16 + l16;
    float s1=0.f, s2=0.f;
    #pragma unroll
    for (int i=0;i<4;i++){
      int row = wr + i*16 + q*4;
      #pragma unroll
      for (int r=0;r<4;r++){
        float v = acc[i][c][r];
        hs[row + r][o] = (_Float16)v;
        s1 += v; s2 = fmaf(v,v,s2);
      }
    }
    s1 += __shfl_xor(s1, 16, 64); s1 += __shfl_xor(s1, 32, 64);
    s2 += __shfl_xor(s2, 16, 64); s2 += __shfl_xor(s2, 32, 64);
    if (q==0){ red1[w][c*16+l16] = s1; red2[w][c*16+l16] = s2; }
  }
  __syncthreads();
  if (LAYER==3){
    // per-center max over the 32 neighbor rows -> M[center][c] (f16).
    if (t<128){
      #pragma unroll
      for (int c4=0;c4<4;c4++){
        _Float16 mx = hs[c4*32][t];
        #pragma unroll
        for (int r=1;r<32;r++){
          _Float16 v = hs[c4*32 + r][t];
          mx = (v > mx) ? v : mx;
        }
        Hout[(size_t)(blk*4 + c4)*128 + t] = mx;   // 256B coalesced per c4
      }
    }
  } else {
    _Float16* dst0 = Hout + (size_t)m0*128;
    #pragma unroll
    for (int j=0;j<8;j++){
      int fi = j*256 + t;
      int row = fi >> 4, col = (fi & 15)*8;
      *(f16x8*)(dst0 + (size_t)fi*8) = *(const f16x8*)&hs[row][col];
    }
  }
  if (t<128){
    int lo = t & 63, g = (t>>6)*2;
    unsafeAtomicAdd(&gs1[b*128+t], red1[g][lo] + red1[g+1][lo]);
    unsafeAtomicAdd(&gs2[b*128+t], red2[g][lo] + red2[g+1][lo]);
  }
}

// ---------------------------------------------------------------------------
// Final (R8): M already holds max_k h (per center, 128 ch). Just norm+relu
// per channel, then fc 128->3. Reads 2 MB instead of 67 MB.
// ---------------------------------------------------------------------------
__global__ __launch_bounds__(128) void final_kernel(
    const void* __restrict__ pc1,
    const _Float16* __restrict__ M,
    const float* __restrict__ gp1, const float* __restrict__ gp2,
    const void* __restrict__ fc_w, const void* __restrict__ fc_b,
    void* __restrict__ outv)
{
  __shared__ float mv[128];
  int blk = blockIdx.x;       // b*1024+s
  int b = blk>>10, s = blk & 1023;
  int o = threadIdx.x;
  const bool f32 = detect_f32((const unsigned short*)pc1);
  float mraw = (float)M[(size_t)blk*128 + o];   // exact f16->f32
  int bo = b*128 + o;
  const float inv = 1.0f/32768.0f;
  float mu_ = gp1[bo]*inv;
  float rs_ = rsqrtf(gp2[bo]*inv - mu_*mu_ + 1e-5f);
  float v = fmaxf((mraw - mu_)*rs_, 0.f);   // == max_k relu(norm(h_k)) exactly
  mv[o] = v;
  __syncthreads();
  if (o<3){
    float acc = ldin(fc_b, o, f32);
    for(int c=0;c<128;c++) acc = fmaf(ldin(fc_w, (size_t)o*128+c, f32), mv[c], acc);
    size_t oi = ((size_t)b*3 + o)*NS + s;
    if (f32) ((float*)outv)[oi] = acc;
    else     ((unsigned short*)outv)[oi] = f2bf(acc);
  }
}

// ---------------------------------------------------------------------------
extern "C" void kernel_launch(void* const* d_in, const int* in_sizes, int n_in,
                              void* d_out, int out_size, void* d_ws, size_t ws_size,
                              hipStream_t stream){
  const void* pc1   = d_in[0];
  const void* feats = d_in[1];
  const void* W1    = d_in[2];
  const void* W2    = d_in[4];
  const void* W3    = d_in[6];
  const void* fcw   = d_in[8];
  const void* fcb   = d_in[9];
  char* ws = (char*)d_ws;
  int*      fps  = (int*)     (ws + 0);          // 32768 B   (sentinel -1)
  float*    nxyz = (float*)   (ws + 32768);      // 98304 B
  int*      knn  = (int*)     (ws + 131072);     // 1048576 B
  float*    st   = (float*)   (ws + 1179648);    // 6*1024*4 = 24576 B  [s1a s2a s1b s2b s1c s2c]
  _Float16* Ha   = (_Float16*)(ws + 1204224);    // 67108864 B
  _Float16* Hb   = (_Float16*)(ws + 68313088);   // 67108864 B (total 135421952)
  _Float16* G    = Hb;  // G (8.9 MB) aliases Hb: read only by conv1, Hb first written by conv2
  _Float16* W1p  = (_Float16*)(ws + 118644736);  // 40960 B, 48 MB into Hb (past G);
                                                 // written by fused, read by conv1,
                                                 // overwritten later by conv2's Hout.

  // sentinel-fill fps_out (-1) so workers can spin on flag==data
  (void)hipMemsetAsync(fps, 0xFF, NB*NS*sizeof(int), stream);

  fps_knn_fused<<<8 + NWORK, 256, 0, stream>>>(pc1, feats, W1, fps, G, W1p, st, nxyz, knn);

  conv_mfma<1><<<NM/128, 256, 0, stream>>>(pc1, G, knn, nxyz,
      (const _Float16*)nullptr, (const float*)nullptr, (const float*)nullptr,
      W1p, Ha, st, st+1024);
  conv_mfma<2><<<NM/128, 256, 0, stream>>>(pc1, G, knn, nxyz,
      Ha, st, st+1024, W2, Hb, st+2048, st+3072);
  // conv3 writes M = per-center max (2 MB) into Ha head
  conv_mfma<3><<<NM/128, 256, 0, stream>>>(pc1, G, knn, nxyz,
      Hb, st+2048, st+3072, W3, Ha, st+4096, st+5120);

  final_kernel<<<NB*NS, 128, 0, stream>>>(pc1, Ha, st+4096, st+5120, fcw, fcb, d_out);
}